// Round 14
// baseline (336.566 us; speedup 1.0000x reference)
//
#include <hip/hip_runtime.h>
#include <hip/hip_bf16.h>

#define DEV __device__ __forceinline__

constexpr int Bc = 2, Nc = 2048, Mc = 2048, DIMc = 512, Hc = 8, FFc = 2048, Ec = 64;
constexpr int CT = 64;            // causal chunk length (tokens)
constexpr int NCc = Nc / CT;      // 32 chunks per sequence
constexpr float LN_EPS = 1e-5f, ATTN_EPS = 1e-6f;

typedef __bf16 bfrag8 __attribute__((ext_vector_type(8)));
typedef float ffrag4 __attribute__((ext_vector_type(4)));
typedef unsigned short u16;

// ---------------- helpers ----------------
DEV u16 f2bf(float v) {
  __hip_bfloat16 h = __float2bfloat16(v);   // RTN-even
  return __builtin_bit_cast(unsigned short, h);
}
DEV float bf2f(u16 u) { return __uint_as_float(((unsigned)u) << 16); }

DEV void gload16(const void* g, void* l) {
  __builtin_amdgcn_global_load_lds(
      (const __attribute__((address_space(1))) void*)g,
      (__attribute__((address_space(3))) void*)l, 16, 0, 0);
}

// XOR swizzle for [64][64] u16 LDS tiles (row stride 128B) — causalC/attn2.
DEV int SW(int r, int c) { return r * 64 + (c ^ ((r & 7) << 3)); }

// GEMM-tile swizzle: [rows][32] u16 (64B rows). 16B-chunk index XORed with
// (row>>1)&3. Zero bank conflicts (verified round 8).
DEV int SWK(int r, int c) { return r * 32 + ((c ^ ((r >> 1) & 3)) << 3); }

// ---------------- dtype detection ----------------
__global__ __launch_bounds__(64) void detect_kernel(const void* x, int* flag) {
  const unsigned short* u = (const unsigned short*)x;
  int tid = threadIdx.x;
  int bad = 0;
#pragma unroll
  for (int i = 0; i < 8; ++i) {
    float v = __uint_as_float(((unsigned)u[tid * 8 + i]) << 16);
    if (!(fabsf(v) <= 1e4f)) bad = 1;   // catches NaN, Inf, garbage
  }
  unsigned long long m = __ballot(bad);
  if (tid == 0) *flag = (m == 0ull) ? 1 : 0;  // 1 = inputs are bf16
}

// ---------------- job structs ----------------
struct ConvJob { const void* src; float* dst; int n; };
struct ConvJobs { ConvJob j[18]; };
struct WJob { const void* src; u16* dst; int K; int N; int tx; int base; };
struct WJobs { WJob j[5]; };

// ---------------- FUSED prep: one launch does all preprocessing -------------------
// Block ranges: [0,896) weight transpose+split; [896,1920) activation splits
// (x -> outA, memory -> outC); [1920,1956) small-array fp32 ingest;
// [1956,2021) zero colsum+ctx2 (replaces hipMemsetAsync). All branches are
// block-uniform; all depend only on *flag (detect_kernel precedes, stream-ordered).
__global__ __launch_bounds__(256) void prep_kernel(WJobs wjobs, ConvJobs cjobs,
    const void* __restrict__ xin, const void* __restrict__ memin,
    u16* __restrict__ outA, u16* __restrict__ outC,
    float* __restrict__ zbase, const int* __restrict__ flag)
{
  const int bf = *flag;
  const int blk = blockIdx.x;
  const int tid = threadIdx.x;
  __shared__ float T[64][65];

  if (blk < 896) {
    // ---- weight KxN (raw) -> B2t (N x 2K bf16) transpose+split ----
    int ji = 0;
#pragma unroll
    for (int t = 1; t < 5; ++t) if (blk >= wjobs.j[t].base) ji = t;
    WJob jb = wjobs.j[ji];
    int tti = blk - jb.base;
    int bx = tti % jb.tx, by = tti / jb.tx;
    const int K = jb.K, N = jb.N;
    const void* W = jb.src;
    u16* B2t = jb.dst;
    int n0 = bx * 64, k0 = by * 64;
#pragma unroll
    for (int j = 0; j < 16; ++j) {
      int idx = tid + 256 * j;
      int kl = idx >> 6, nl = idx & 63;
      size_t gi = (size_t)(k0 + kl) * N + n0 + nl;
      T[kl][nl] = bf ? bf2f(((const u16*)W)[gi]) : ((const float*)W)[gi];
    }
    __syncthreads();
#pragma unroll
    for (int j = 0; j < 16; ++j) {
      int idx = tid + 256 * j;
      int nl = idx >> 6, kl = idx & 63;
      float v = T[kl][nl];
      u16 hi = f2bf(v);
      u16 lo = f2bf(v - bf2f(hi));
      size_t rb = (size_t)(n0 + nl) * 2 * K + k0 + kl;
      B2t[rb]     = hi;
      B2t[rb + K] = lo;
    }
  } else if (blk < 1920) {
    // ---- raw activation -> [hi|lo] split (x and memory, 512 blocks each) ----
    int sub = blk - 896;
    int which = sub >> 9;           // 0: x, 1: memory
    int bx = sub & 511;
    const void* in = which ? memin : xin;
    u16* out = which ? outC : outA;
    const int K = DIMc;             // rows of length 512
    const int total = Bc * Nc * DIMc;
    int n8 = total >> 3;
    int stride = 512 * 256;
    for (int ii = bx * 256 + tid; ii < n8; ii += stride) {
      int i = ii * 8;
      float v[8];
      if (bf) {
        uint4 a = ((const uint4*)in)[ii];
        unsigned w[4] = {a.x, a.y, a.z, a.w};
#pragma unroll
        for (int j = 0; j < 4; ++j) {
          v[2 * j]     = bf2f((u16)(w[j] & 0xffff));
          v[2 * j + 1] = bf2f((u16)(w[j] >> 16));
        }
      } else {
        float4 a = ((const float4*)in)[2 * ii];
        float4 b = ((const float4*)in)[2 * ii + 1];
        v[0] = a.x; v[1] = a.y; v[2] = a.z; v[3] = a.w;
        v[4] = b.x; v[5] = b.y; v[6] = b.z; v[7] = b.w;
      }
      unsigned hw[4], lw[4];
#pragma unroll
      for (int j = 0; j < 4; ++j) {
        u16 h0 = f2bf(v[2 * j]),     l0 = f2bf(v[2 * j]     - bf2f(f2bf(v[2 * j])));
        u16 h1 = f2bf(v[2 * j + 1]), l1 = f2bf(v[2 * j + 1] - bf2f(f2bf(v[2 * j + 1])));
        hw[j] = (unsigned)h0 | ((unsigned)h1 << 16);
        lw[j] = (unsigned)l0 | ((unsigned)l1 << 16);
      }
      int row = i >> 9, k = i & (K - 1);
      size_t rb = (size_t)row * 2 * K + k;
      *(uint4*)&out[rb]     = uint4{hw[0], hw[1], hw[2], hw[3]};
      *(uint4*)&out[rb + K] = uint4{lw[0], lw[1], lw[2], lw[3]};
    }
  } else if (blk < 1956) {
    // ---- small-array fp32 ingest (biases, LN params): 2 blocks per job ----
    int s = blk - 1920;
    ConvJob jb = cjobs.j[s >> 1];
    int bx = s & 1;
    int n8 = jb.n >> 3;
    int stride = 2 * 256;
    for (int i = bx * 256 + tid; i < n8; i += stride) {
      float o[8];
      if (bf) {
        uint4 a = ((const uint4*)jb.src)[i];
        unsigned w[4] = {a.x, a.y, a.z, a.w};
#pragma unroll
        for (int j = 0; j < 4; ++j) {
          o[2 * j]     = bf2f((u16)(w[j] & 0xffff));
          o[2 * j + 1] = bf2f((u16)(w[j] >> 16));
        }
      } else {
        float4 a = ((const float4*)jb.src)[2 * i];
        float4 b = ((const float4*)jb.src)[2 * i + 1];
        o[0] = a.x; o[1] = a.y; o[2] = a.z; o[3] = a.w;
        o[4] = b.x; o[5] = b.y; o[6] = b.z; o[7] = b.w;
      }
      float4* d = (float4*)jb.dst;
      d[2 * i]     = float4{o[0], o[1], o[2], o[3]};
      d[2 * i + 1] = float4{o[4], o[5], o[6], o[7]};
    }
  } else {
    // ---- zero colsum + ctx2: 66560 floats = 16640 float4 = 65 blocks x 256 ----
    int zi = (blk - 1956) * 256 + tid;
    ((float4*)zbase)[zi] = float4{0.f, 0.f, 0.f, 0.f};
  }
}

// ---------------- MFMA GEMM: C[M,N] = A2[M,2K] @ B2t[N,2K]^T ----------------
// COUNTED-VMCNT double-buffered pipeline (T4). BN=128 gives FM=FN=4: 32-48 MFMA
// per K-step vs 12-16 ds_read_b128 (ratio ~2.7). vmcnt literals per BN/product-set.
// Product set wave-uniform: fp32 = 3 products; bf16 = Bl==0; bf16+A_EXACT = 1.
// SWK swizzle both sides (0 conflicts). Bijective XCD swizzle.
// OUTMODE 0: fp32 C (+bias)(+res)(relu). OUTMODE 1: split [hi|lo] bf16 out
// (row 2N). OUTMODE 2: raw fp32 partial (split-K). Requires nt even (all sites).
template<int BM, int BN, int SPLITK, int OUTMODE, bool RELU, bool ADD_RES, bool A_EXACT>
__global__ __launch_bounds__(256) void gemm_mfma(
    const u16* __restrict__ A2, const u16* __restrict__ B2t,
    const float* __restrict__ bias, const float* __restrict__ res,
    float* __restrict__ Cf, u16* __restrict__ C2,
    int N, int K, const int* __restrict__ flagp)
{
  constexpr int WM = BM / 2, WN = BN / 2, FM = WM / 16, FN = WN / 16;
  __shared__ u16 A0h[BM * 32], A0l[BM * 32], B0h[BN * 32], B0l[BN * 32];
  __shared__ u16 A1h[BM * 32], A1l[BM * 32], B1h[BN * 32], B1l[BN * 32];
  const int bf = *flagp;
  const bool useBl = (bf == 0);             // weights exact when bf16
  const bool useAl = (bf == 0) || !A_EXACT; // raw-input A exact when bf16
  const int tid = threadIdx.x;
  const int lane = tid & 63, wid = tid >> 6;
  const int wr = wid >> 1, wc = wid & 1;
  const int gx = gridDim.x, gy = gridDim.y;
  const int nwg = gx * gy * gridDim.z;
  const int flat = (blockIdx.z * gy + blockIdx.y) * gx + blockIdx.x;
  const int v = (flat & 7) * (nwg >> 3) + (flat >> 3);
  const int bx = v % gx;
  const int rest = v / gx;
  const int by = rest % gy;
  const int bz = rest / gy;
  const int row0 = by * BM, col0 = bx * BN;
  const int Mtot = gy * BM;
  const int sr = lane >> 2;
  const int skl = (((lane & 3) ^ ((sr >> 1) & 3)) << 3);   // inverse-swz source chunk
  const int ar = lane & 15, kc = lane >> 4;                // fragment coords
  const size_t strA = (size_t)2 * K;

  ffrag4 acc[FM][FN];
#pragma unroll
  for (int m = 0; m < FM; ++m)
#pragma unroll
    for (int n = 0; n < FN; ++n) acc[m][n] = ffrag4{0.f, 0.f, 0.f, 0.f};

  const int Kseg = K / SPLITK;
  const int kbeg = bz * Kseg;
  const int nt = Kseg / 32;   // even at every call site

#define FENCE_ asm volatile("" ::: "memory")
#define BAR_ do { FENCE_; __builtin_amdgcn_s_barrier(); FENCE_; } while (0)
#define WAITV__(n) asm volatile("s_waitcnt vmcnt(" #n ")" ::: "memory")
#define WAITV_(n) WAITV__(n)

#define STAGE_(UA, UB, AH, AL, BH, BL, KK) do {                                      \
    for (int r = wid; r < BM / 16; r += 4) {                                         \
      gload16(&A2[(size_t)(row0 + r * 16 + sr) * strA + (KK) + skl],     &AH[r * 16 * 32]); \
      if (UA)                                                                        \
        gload16(&A2[(size_t)(row0 + r * 16 + sr) * strA + K + (KK) + skl], &AL[r * 16 * 32]); \
    }                                                                                \
    for (int r = wid; r < BN / 16; r += 4) {                                         \
      gload16(&B2t[(size_t)(col0 + r * 16 + sr) * strA + (KK) + skl],     &BH[r * 16 * 32]); \
      if (UB)                                                                        \
        gload16(&B2t[(size_t)(col0 + r * 16 + sr) * strA + K + (KK) + skl], &BL[r * 16 * 32]); \
    } } while (0)

#define COMPUTE_(UA, UB, AH, AL, BH, BL) do {                                        \
    bfrag8 afh[FM], bwh[FN];                                                         \
    _Pragma("unroll")                                                                \
    for (int m = 0; m < FM; ++m)                                                     \
      afh[m] = *(const bfrag8*)&AH[SWK(wr * WM + m * 16 + ar, kc)];                  \
    _Pragma("unroll")                                                                \
    for (int n = 0; n < FN; ++n)                                                     \
      bwh[n] = *(const bfrag8*)&BH[SWK(wc * WN + n * 16 + ar, kc)];                  \
    _Pragma("unroll")                                                                \
    for (int m = 0; m < FM; ++m)                                                     \
      _Pragma("unroll")                                                              \
      for (int n = 0; n < FN; ++n)                                                   \
        acc[m][n] = __builtin_amdgcn_mfma_f32_16x16x32_bf16(afh[m], bwh[n], acc[m][n], 0, 0, 0); \
    if (UB) {                                                                        \
      bfrag8 bwl[FN];                                                                \
      _Pragma("unroll")                                                              \
      for (int n = 0; n < FN; ++n)                                                   \
        bwl[n] = *(const bfrag8*)&BL[SWK(wc * WN + n * 16 + ar, kc)];                \
      _Pragma("unroll")                                                              \
      for (int m = 0; m < FM; ++m)                                                   \
        _Pragma("unroll")                                                            \
        for (int n = 0; n < FN; ++n)                                                 \
          acc[m][n] = __builtin_amdgcn_mfma_f32_16x16x32_bf16(afh[m], bwl[n], acc[m][n], 0, 0, 0); \
    }                                                                                \
    if (UA) {                                                                        \
      bfrag8 afl[FM];                                                                \
      _Pragma("unroll")                                                              \
      for (int m = 0; m < FM; ++m)                                                   \
        afl[m] = *(const bfrag8*)&AL[SWK(wr * WM + m * 16 + ar, kc)];                \
      _Pragma("unroll")                                                              \
      for (int m = 0; m < FM; ++m)                                                   \
        _Pragma("unroll")                                                            \
        for (int n = 0; n < FN; ++n)                                                 \
          acc[m][n] = __builtin_amdgcn_mfma_f32_16x16x32_bf16(afl[m], bwh[n], acc[m][n], 0, 0, 0); \
    } } while (0)

  // Pipeline: tile t lives in buf(t&1). Per K-step: {stage t+1, wait vmcnt(L)
  // [t's loads done, t+1's in flight], barrier, compute t, barrier}.
#define KLOOP_(L, UA, UB) do {                                                       \
    STAGE_(UA, UB, A0h, A0l, B0h, B0l, kbeg);                                        \
    for (int t = 0; t < nt; t += 2) {                                                \
      STAGE_(UA, UB, A1h, A1l, B1h, B1l, kbeg + (t + 1) * 32);                       \
      WAITV_(L);                                                                     \
      BAR_;                                                                          \
      COMPUTE_(UA, UB, A0h, A0l, B0h, B0l);                                          \
      BAR_;                                                                          \
      if (t + 2 < nt) { STAGE_(UA, UB, A0h, A0l, B0h, B0l, kbeg + (t + 2) * 32); WAITV_(L); } \
      else            { WAITV_(0); }                                                 \
      BAR_;                                                                          \
      COMPUTE_(UA, UB, A1h, A1l, B1h, B1l);                                          \
      BAR_;                                                                          \
    } } while (0)

  // L = per-wave loads of one stage: A = (BM/64)*(1+UA), B = (BN/64)*(1+UB).
  if constexpr (BN == 128) {
    if (useAl && useBl)      KLOOP_(8, 1, 1);   // fp32: 3 products
    else if (useAl)          KLOOP_(6, 1, 0);   // bf16, A inexact: 2 products
    else                     KLOOP_(4, 0, 0);   // bf16, A exact: 1 product
  } else {
    if (useAl && useBl)      KLOOP_(6, 1, 1);
    else if (useAl)          KLOOP_(5, 1, 0);
    else                     KLOOP_(3, 0, 0);
  }

#undef KLOOP_
#undef COMPUTE_
#undef STAGE_
#undef WAITV_
#undef WAITV__
#undef BAR_
#undef FENCE_

#pragma unroll
  for (int m = 0; m < FM; ++m) {
    int rbase = row0 + wr * WM + m * 16 + (lane >> 4) * 4;
#pragma unroll
    for (int n = 0; n < FN; ++n) {
      int col = col0 + wc * WN + n * 16 + ar;
#pragma unroll
      for (int u = 0; u < 4; ++u) {
        int row = rbase + u;
        float val = acc[m][n][u];
        if constexpr (OUTMODE == 2) {
          Cf[((size_t)bz * Mtot + row) * N + col] = val;
        } else {
          val += bias[col];
          if (ADD_RES) val += res[(size_t)row * N + col];
          if (RELU) val = fmaxf(val, 0.f);
          if constexpr (OUTMODE == 0) {
            Cf[(size_t)row * N + col] = val;
          } else {
            u16 hi = f2bf(val);
            u16 lo = f2bf(val - bf2f(hi));
            size_t rb = (size_t)row * 2 * N;
            C2[rb + col]     = hi;
            C2[rb + N + col] = lo;
          }
        }
      }
    }
  }
}

// ---------------- layernorm over last dim (512), optional residual ----------------
// RAW_RES: residual read straight from a raw (bf16|fp32) input buffer.
// OUTSPLIT: also emit [hi|lo] bf16 split rows (len 1024) for the next GEMM's A.
template<bool HAS_RES, bool RAW_RES, bool FINAL, bool OUTSPLIT>
__global__ __launch_bounds__(256) void ln_kernel(
    const float* __restrict__ in, const void* __restrict__ res,
    const float* __restrict__ g, const float* __restrict__ b,
    void* __restrict__ out, u16* __restrict__ out2, const int* __restrict__ flag)
{
  int row = blockIdx.x, tid = threadIdx.x;
  size_t base = (size_t)row * DIMc;
  float x0 = in[base + tid], x1 = in[base + tid + 256];
  if (HAS_RES) {
    if (RAW_RES) {
      if (*flag) {
        x0 += bf2f(((const u16*)res)[base + tid]);
        x1 += bf2f(((const u16*)res)[base + tid + 256]);
      } else {
        x0 += ((const float*)res)[base + tid];
        x1 += ((const float*)res)[base + tid + 256];
      }
    } else {
      x0 += ((const float*)res)[base + tid];
      x1 += ((const float*)res)[base + tid + 256];
    }
  }
  float s1 = x0 + x1, s2 = x0 * x0 + x1 * x1;
#pragma unroll
  for (int off = 1; off < 64; off <<= 1) { s1 += __shfl_xor(s1, off); s2 += __shfl_xor(s2, off); }
  __shared__ float p1[4], p2[4], stat[2];
  if ((tid & 63) == 0) { p1[tid >> 6] = s1; p2[tid >> 6] = s2; }
  __syncthreads();
  if (tid == 0) {
    float t1 = p1[0] + p1[1] + p1[2] + p1[3];
    float t2 = p2[0] + p2[1] + p2[2] + p2[3];
    float mu = t1 / DIMc;
    float var = t2 / DIMc - mu * mu;
    stat[0] = mu; stat[1] = rsqrtf(var + LN_EPS);
  }
  __syncthreads();
  float mu = stat[0], rv = stat[1];
  float y0 = (x0 - mu) * rv * g[tid] + b[tid];
  float y1 = (x1 - mu) * rv * g[tid + 256] + b[tid + 256];
  if (FINAL) {
    if (*flag) {
      __hip_bfloat16* o = (__hip_bfloat16*)out;
      o[base + tid] = __float2bfloat16(y0);
      o[base + tid + 256] = __float2bfloat16(y1);
    } else {
      float* o = (float*)out;
      o[base + tid] = y0;
      o[base + tid + 256] = y1;
    }
  } else {
    float* o = (float*)out;
    o[base + tid] = y0;
    o[base + tid + 256] = y1;
  }
  if (OUTSPLIT) {
    size_t rb = (size_t)row * 1024;
    u16 h0 = f2bf(y0);
    out2[rb + tid] = h0;
    out2[rb + 512 + tid] = f2bf(y0 - bf2f(h0));
    u16 h1 = f2bf(y1);
    out2[rb + tid + 256] = h1;
    out2[rb + 512 + tid + 256] = f2bf(y1 - bf2f(h1));
  }
}

// ---------------- fused split-K reduce (P=4) + bias + residual + LN3 -> d_out ------
__global__ __launch_bounds__(256) void ln3_fused(const float* __restrict__ part,
    const float* __restrict__ bias, const float* __restrict__ res,
    const float* __restrict__ g, const float* __restrict__ b,
    void* __restrict__ out, const int* __restrict__ flag)
{
  int row = blockIdx.x, tid = threadIdx.x;
  size_t base = (size_t)row * DIMc;
  float x0 = bias[tid] + res[base + tid];
  float x1 = bias[tid + 256] + res[base + tid + 256];
#pragma unroll
  for (int p = 0; p < 4; ++p) {
    x0 += part[(size_t)p * 2097152 + base + tid];
    x1 += part[(size_t)p * 2097152 + base + tid + 256];
  }
  float s1 = x0 + x1, s2 = x0 * x0 + x1 * x1;
#pragma unroll
  for (int off = 1; off < 64; off <<= 1) { s1 += __shfl_xor(s1, off); s2 += __shfl_xor(s2, off); }
  __shared__ float p1[4], p2[4], stat[2];
  if ((tid & 63) == 0) { p1[tid >> 6] = s1; p2[tid >> 6] = s2; }
  __syncthreads();
  if (tid == 0) {
    float t1 = p1[0] + p1[1] + p1[2] + p1[3];
    float t2 = p2[0] + p2[1] + p2[2] + p2[3];
    float mu = t1 / DIMc;
    float var = t2 / DIMc - mu * mu;
    stat[0] = mu; stat[1] = rsqrtf(var + LN_EPS);
  }
  __syncthreads();
  float mu = stat[0], rv = stat[1];
  float y0 = (x0 - mu) * rv * g[tid] + b[tid];
  float y1 = (x1 - mu) * rv * g[tid + 256] + b[tid + 256];
  if (*flag) {
    __hip_bfloat16* o = (__hip_bfloat16*)out;
    o[base + tid] = __float2bfloat16(y0);
    o[base + tid + 256] = __float2bfloat16(y1);
  } else {
    float* o = (float*)out;
    o[base + tid] = y0;
    o[base + tid + 256] = y1;
  }
}

// ---------------- causal linear attention, pass A: per-chunk KV sums ----------------
// Writes chunkKV TRANSPOSED: chunkKVT[e][d] = sum_t ks[t][d]*vs[t][e]
__global__ __launch_bounds__(256) void causalA(const float* __restrict__ qvk,
    float* __restrict__ chunkKVT, float* __restrict__ chunkKs)
{
  int c = blockIdx.x, bh = blockIdx.y;
  int b = bh >> 3, h = bh & 7;
  __shared__ float ks[CT][Ec];
  __shared__ float vs[CT][Ec];
  int tid = threadIdx.x;
#pragma unroll
  for (int j = 0; j < 16; ++j) {
    int i = tid + 256 * j;
    int t = i >> 6, d = i & 63;
    size_t rowbase = ((size_t)b * Nc + c * CT + t) * (3 * DIMc);
    ks[t][d] = __expf(qvk[rowbase + 2 * DIMc + h * Ec + d]);
    vs[t][d] = qvk[rowbase + DIMc + h * Ec + d];
  }
  __syncthreads();
  int e = tid & 63, d0 = tid >> 6;
  float acc[16] = {};
  for (int t = 0; t < CT; ++t) {
    float ve = vs[t][e];
#pragma unroll
    for (int j = 0; j < 16; ++j) acc[j] += ks[t][d0 + 4 * j] * ve;
  }
  size_t obase = ((size_t)bh * NCc + c) * (Ec * Ec);
#pragma unroll
  for (int j = 0; j < 16; ++j) chunkKVT[obase + (size_t)e * Ec + (d0 + 4 * j)] = acc[j];
  if (tid < Ec) {
    float s = 0;
    for (int t = 0; t < CT; ++t) s += ks[t][tid];
    chunkKs[((size_t)bh * NCc + c) * Ec + tid] = s;
  }
}

// ---------------- pass B: exclusive prefix over chunks (parallelized) ----------------
__global__ __launch_bounds__(256) void causalB(float* __restrict__ chunkKV,
                                               float* __restrict__ chunkKs)
{
  int bh = blockIdx.x, grp = blockIdx.y, tid = threadIdx.x;
  if (grp < 16) {
    int idx = grp * 256 + tid;
    float run = 0;
    size_t base = (size_t)bh * NCc * Ec * Ec + idx;
#pragma unroll
    for (int c = 0; c < NCc; ++c) {
      float t = chunkKV[base + (size_t)c * Ec * Ec];
      chunkKV[base + (size_t)c * Ec * Ec] = run;
      run += t;
    }
  } else if (tid < Ec) {
    float run = 0;
    size_t base = (size_t)bh * NCc * Ec + tid;
#pragma unroll
    for (int c = 0; c < NCc; ++c) {
      float t = chunkKs[base + (size_t)c * Ec];
      chunkKs[base + (size_t)c * Ec] = run;
      run += t;
    }
  }
}

// ---------------- pass C: per-token outputs via MFMA ----------------
__global__ __launch_bounds__(256) void causalC(const float* __restrict__ qvk,
    const float* __restrict__ chunkKVT, const float* __restrict__ chunkKs,
    float* __restrict__ attn_out)
{
  int c = blockIdx.x, bh = blockIdx.y;
  int b = bh >> 3, h = bh & 7;
  __shared__ u16 qsh[64 * 64], qsl[64 * 64];   // A: qs[t][d]
  __shared__ u16 ksPh[64 * 64], ksPl[64 * 64]; // B: ks[tau][d]  ->  A: Pm[t][tau]
  __shared__ u16 STh[64 * 64], STl[64 * 64];   // B: S^T[e][d]
  __shared__ u16 VTh[64 * 72], VTl[64 * 72];   // B: V^T[e][tau], pad 72
  __shared__ float kpre[Ec], r0[CT], dinv[CT];
  int tid = threadIdx.x;
  int lane = tid & 63, w = tid >> 6;
  const int ar = lane & 15, kb = (lane >> 4) * 8;
  size_t kvb = (size_t)bh * NCc + c;

  if (tid < Ec) kpre[tid] = chunkKs[kvb * Ec + tid] + ATTN_EPS;

  float qreg[16];
#pragma unroll
  for (int j = 0; j < 16; ++j) {
    int t = w * 16 + j, d = lane;
    size_t rowbase = ((size_t)b * Nc + c * CT + t) * (3 * DIMc);
    qreg[j] = qvk[rowbase + h * Ec + d];
    float kv = __expf(qvk[rowbase + 2 * DIMc + h * Ec + d]);
    u16 hi = f2bf(kv);
    ksPh[SW(t, d)] = hi; ksPl[SW(t, d)] = f2bf(kv - bf2f(hi));
    float vv = qvk[rowbase + DIMc + h * Ec + d];
    hi = f2bf(vv);
    VTh[d * 72 + t] = hi; VTl[d * 72 + t] = f2bf(vv - bf2f(hi));
    float sv = chunkKVT[kvb * (Ec * Ec) + (size_t)t * Ec + d];  // row e=t of S^T
    hi = f2bf(sv);
    STh[SW(t, d)] = hi; STl[SW(t, d)] = f2bf(sv - bf2f(hi));
  }
  __syncthreads();

  for (int ti = 0; ti < 16; ++ti) {
    int t = w * 16 + ti;
    float qv = qreg[ti];
    float mx = qv;
#pragma unroll
    for (int off = 1; off < 64; off <<= 1) mx = fmaxf(mx, __shfl_xor(mx, off));
    float ex = __expf(qv - mx);
    float ssum = ex;
#pragma unroll
    for (int off = 1; off < 64; off <<= 1) ssum += __shfl_xor(ssum, off);
    float qs = ex / ssum * 0.125f;
    float qk = qs * kpre[lane];
#pragma unroll
    for (int off = 1; off < 64; off <<= 1) qk += __shfl_xor(qk, off);
    if (lane == 0) r0[t] = qk;
    u16 hi = f2bf(qs);
    qsh[SW(t, lane)] = hi; qsl[SW(t, lane)] = f2bf(qs - bf2f(hi));
  }
  __syncthreads();

  ffrag4 pacc[4];
#pragma unroll
  for (int ct = 0; ct < 4; ++ct) pacc[ct] = ffrag4{0.f, 0.f, 0.f, 0.f};
#pragma unroll
  for (int ct = 0; ct < 4; ++ct)
#pragma unroll
    for (int k2 = 0; k2 < 64; k2 += 32) {
      bfrag8 ah = *(const bfrag8*)&qsh[SW(w * 16 + ar, k2 + kb)];
      bfrag8 al = *(const bfrag8*)&qsl[SW(w * 16 + ar, k2 + kb)];
      bfrag8 bh_ = *(const bfrag8*)&ksPh[SW(ct * 16 + ar, k2 + kb)];
      bfrag8 bl_ = *(const bfrag8*)&ksPl[SW(ct * 16 + ar, k2 + kb)];
      pacc[ct] = __builtin_amdgcn_mfma_f32_16x16x32_bf16(ah, bh_, pacc[ct], 0, 0, 0);
      pacc[ct] = __builtin_amdgcn_mfma_f32_16x16x32_bf16(ah, bl_, pacc[ct], 0, 0, 0);
      pacc[ct] = __builtin_amdgcn_mfma_f32_16x16x32_bf16(al, bh_, pacc[ct], 0, 0, 0);
    }
  __syncthreads();

  float rs[4] = {0.f, 0.f, 0.f, 0.f};
#pragma unroll
  for (int ct = 0; ct < 4; ++ct) {
    int tau = ct * 16 + ar;
#pragma unroll
    for (int u = 0; u < 4; ++u) {
      int t = w * 16 + (lane >> 4) * 4 + u;
      float pv = (tau <= t) ? pacc[ct][u] : 0.f;
      rs[u] += pv;
      u16 hi = f2bf(pv);
      ksPh[SW(t, tau)] = hi; ksPl[SW(t, tau)] = f2bf(pv - bf2f(hi));
    }
  }
#pragma unroll
  for (int u = 0; u < 4; ++u) {
    float vv = rs[u];
    vv += __shfl_xor(vv, 1); vv += __shfl_xor(vv, 2);
    vv += __shfl_xor(vv, 4); vv += __shfl_xor(vv, 8);
    if (ar == 0) {
      int t = w * 16 + (lane >> 4) * 4 + u;
      dinv[t] = 1.f / (r0[t] + vv);
    }
  }
  __syncthreads();

#pragma unroll
  for (int et = 0; et < 4; ++et) {
    ffrag4 oacc = ffrag4{0.f, 0.f, 0.f, 0.f};
#pragma unroll
    for (int k2 = 0; k2 < 64; k2 += 32) {
      bfrag8 ah = *(const bfrag8*)&qsh[SW(w * 16 + ar, k2 + kb)];
      bfrag8 al = *(const bfrag8*)&qsl[SW(w * 16 + ar, k2 + kb)];
      bfrag8 bh_ = *(const bfrag8*)&STh[SW(et * 16 + ar, k2 + kb)];
      bfrag8 bl_ = *(const bfrag8*)&STl[SW(et * 16 + ar, k2 + kb)];
      oacc = __builtin_amdgcn_mfma_f32_16x16x32_bf16(ah, bh_, oacc, 0, 0, 0);
      oacc = __builtin_amdgcn_mfma_f32_16x16x32_bf16(ah, bl_, oacc, 0, 0, 0);
      oacc = __builtin_amdgcn_mfma_f32_16x16x32_bf16(al, bh_, oacc, 0, 0, 0);
      bfrag8 ph = *(const bfrag8*)&ksPh[SW(w * 16 + ar, k2 + kb)];
      bfrag8 pl = *(const bfrag8*)&ksPl[SW(w * 16 + ar, k2 + kb)];
      bfrag8 vh = *(const bfrag8*)&VTh[(et * 16 + ar) * 72 + k2 + kb];
      bfrag8 vl = *(const bfrag8*)&VTl[(et * 16 + ar) * 72 + k2 + kb];
      oacc = __builtin_amdgcn_mfma_f32_16x16x32_bf16(ph, vh, oacc, 0, 0, 0);
      oacc = __builtin_amdgcn_mfma_f32_16x16x32_bf16(ph, vl, oacc, 0, 0, 0);
      oacc = __builtin_amdgcn_mfma_f32_16x16x32_bf16(pl, vh, oacc, 0, 0, 0);
    }
    int e = et * 16 + ar;
#pragma unroll
    for (int u = 0; u < 4; ++u) {
      int t = w * 16 + (lane >> 4) * 4 + u;
      attn_out[((size_t)b * Nc + c * CT + t) * DIMc + h * Ec + e] = oacc[u] * dinv[t];
    }
  }
}

// ---------------- cross-attn: ctxT[e][d] += sum_m exp(k2)[m,d] * v2[m,e]  (+colsum) ----
__global__ __launch_bounds__(256) void ctx_kernel(const float* __restrict__ kvbuf,
    float* __restrict__ colsum, float* __restrict__ ctxT)
{
  int slab = blockIdx.x, bh = blockIdx.y;
  int b = bh >> 3, h = bh & 7;
  __shared__ float ks[64][Ec];
  __shared__ float vs[64][Ec];
  int tid = threadIdx.x;
#pragma unroll
  for (int j = 0; j < 16; ++j) {
    int i = tid + 256 * j;
    int m = i >> 6, d = i & 63;
    size_t rowbase = ((size_t)b * Mc + slab * 64 + m) * (2 * DIMc);
    ks[m][d] = __expf(kvbuf[rowbase + h * Ec + d]);
    vs[m][d] = kvbuf[rowbase + DIMc + h * Ec + d];
  }
  __syncthreads();
  int d = tid & 63, e0 = tid >> 6;   // lane owns column d; wave owns e-band
  float acc[16] = {};
  for (int m = 0; m < 64; ++m) {
    float kd = ks[m][d];
#pragma unroll
    for (int j = 0; j < 16; ++j) acc[j] += kd * vs[m][e0 + 4 * j];
  }
  size_t obase = (size_t)bh * Ec * Ec;
#pragma unroll
  for (int j = 0; j < 16; ++j)
    atomicAdd(&ctxT[obase + (size_t)(e0 + 4 * j) * Ec + d], acc[j]);  // coalesced over d
  int w = tid >> 6, lane = tid & 63;
  float s = 0;
#pragma unroll
  for (int m = 0; m < 16; ++m) s += ks[w * 16 + m][lane];
  __shared__ float p[4][Ec];
  p[w][lane] = s;
  __syncthreads();
  if (tid < Ec)
    atomicAdd(&colsum[(size_t)bh * Ec + tid], p[0][tid] + p[1][tid] + p[2][tid] + p[3][tid]);
}

// ---------------- cross-attn via MFMA, fused split-K reduce of q2 ----------------
__global__ __launch_bounds__(256) void attn2_kernel(const float* __restrict__ q2part,
    const float* __restrict__ bq, const float* __restrict__ ctxT,
    const float* __restrict__ colsum, float* __restrict__ out)
{
  int tc = blockIdx.x, bh = blockIdx.y;
  int b = bh >> 3, h = bh & 7;
  __shared__ u16 qsh[64 * 64], qsl[64 * 64];   // A: qs[t][d]
  __shared__ u16 cth[64 * 64], ctl[64 * 64];   // B: ctxT[e][d] (normalized)
  int tid = threadIdx.x;
  int lane = tid & 63, w = tid >> 6;
  const int ar = lane & 15, kb = (lane >> 4) * 8;
  const float bqv = bq[h * Ec + lane];

  // stage normalized ctxT split into LDS
#pragma unroll
  for (int j = 0; j < 16; ++j) {
    int i = tid + 256 * j;
    int r = i >> 6, d = i & 63;
    float v = ctxT[(size_t)bh * Ec * Ec + i] / colsum[(size_t)bh * Ec + d];
    u16 hi = f2bf(v);
    cth[SW(r, d)] = hi; ctl[SW(r, d)] = f2bf(v - bf2f(hi));
  }
  // softmax for this wave's 16 tokens; write qs split
  for (int ti = 0; ti < 16; ++ti) {
    int t = tc * 64 + w * 16 + ti;
    size_t qi = ((size_t)b * Nc + t) * DIMc + h * Ec + lane;
    float qv = q2part[qi] + q2part[(size_t)2097152 + qi] + bqv;
    float mx = qv;
#pragma unroll
    for (int off = 1; off < 64; off <<= 1) mx = fmaxf(mx, __shfl_xor(mx, off));
    float ex = __expf(qv - mx);
    float ssum = ex;
#pragma unroll
    for (int off = 1; off < 64; off <<= 1) ssum += __shfl_xor(ssum, off);
    float qs = ex / ssum * 0.125f;
    u16 hi = f2bf(qs);
    qsh[SW(w * 16 + ti, lane)] = hi; qsl[SW(w * 16 + ti, lane)] = f2bf(qs - bf2f(hi));
  }
  __syncthreads();

#pragma unroll
  for (int et = 0; et < 4; ++et) {
    ffrag4 oacc = ffrag4{0.f, 0.f, 0.f, 0.f};
#pragma unroll
    for (int k2 = 0; k2 < 64; k2 += 32) {
      bfrag8 ah = *(const bfrag8*)&qsh[SW(w * 16 + ar, k2 + kb)];
      bfrag8 al = *(const bfrag8*)&qsl[SW(w * 16 + ar, k2 + kb)];
      bfrag8 bh_ = *(const bfrag8*)&cth[SW(et * 16 + ar, k2 + kb)];
      bfrag8 bl_ = *(const bfrag8*)&ctl[SW(et * 16 + ar, k2 + kb)];
      oacc = __builtin_amdgcn_mfma_f32_16x16x32_bf16(ah, bh_, oacc, 0, 0, 0);
      oacc = __builtin_amdgcn_mfma_f32_16x16x32_bf16(ah, bl_, oacc, 0, 0, 0);
      oacc = __builtin_amdgcn_mfma_f32_16x16x32_bf16(al, bh_, oacc, 0, 0, 0);
    }
    int e = et * 16 + ar;
#pragma unroll
    for (int u = 0; u < 4; ++u) {
      int t = tc * 64 + w * 16 + (lane >> 4) * 4 + u;
      out[((size_t)b * Nc + t) * DIMc + h * Ec + e] = oacc[u];
    }
  }
}

extern "C" void kernel_launch(void* const* d_in, const int* in_sizes, int n_in,
                              void* d_out, int out_size, void* d_ws, size_t ws_size,
                              hipStream_t stream)
{
  float* ws = (float*)d_ws;
  int* flag = (int*)ws;
  float* conv = ws + 64;

  float* cin[18];
  size_t off = 0;
  for (int i = 0; i < 18; ++i) { cin[i] = conv + off; off += (size_t)in_sizes[i]; }
  float* pipe = conv + off;

  const size_t SZ_ROW = (size_t)Bc * Nc * DIMc;            // 2,097,152
  const size_t SZ_KV  = (size_t)Bc * Mc * 2 * DIMc;        // 4,194,304
  const size_t SZ_R0  = 12582912;                          // region0 span (f-eq)

  float* region0 = pipe;
  float* qvk     = region0;                   // live: gemm1 .. causalC
  float* kvbuf   = region0;                   // live: kvGEMM .. ctx_kernel
  u16*   O2ff    = (u16*)region0;             // live: ff1 .. ff2 ([hi|lo], 8.39M f-eq)
  float* out1    = region0 + SZ_R0;           // live: LN1 .. LN2
  float* attn_o  = out1 + SZ_ROW;             // attn_o -> attn2_o -> ybuf
  float* r3      = attn_o + SZ_ROW;           // chunkKV
  float* chunkKV = r3;
  float* chunkKs = r3 + SZ_ROW;                                   // 32768
  float* colsum  = chunkKs + (size_t)Bc * Hc * NCc * Ec;          // 1024
  float* ctx2    = colsum + (size_t)Bc * Hc * Ec;                 // 65536 (transposed)
  float* ybuf    = attn_o;
  float* attn2_o = attn_o;

  u16* B2_qvk = (u16*)(ctx2 + (size_t)Bc * Hc * Ec * Ec);
  u16* B2_kv  = B2_qvk + (size_t)(3 * DIMc) * (2 * DIMc);   // 1536 x 1024
  u16* B2_q   = B2_kv  + (size_t)(2 * DIMc) * (2 * DIMc);   // 1024 x 1024
  u16* B2_ff1 = B2_q   + (size_t)DIMc * (2 * DIMc);         // 512 x 1024
  u16* B2_ff2 = B2_ff1 + (size_t)FFc  * (2 * DIMc);         // 2048 x 1024
  u16* A2slotA = B2_ff2 + (size_t)DIMc * (2 * FFc);         // 4096 x 1024 (x -> ybuf)
  u16* A2slotB = A2slotA + (size_t)4096 * 1024;             // 4096 x 1024 (out1)
  u16* A2slotC = A2slotB + (size_t)4096 * 1024;             // 4096 x 1024 (memory)
  float* partials = (float*)(A2slotC + (size_t)4096 * 1024);// 4 x 2,097,152 fp32
  (void)ws_size; (void)n_in; (void)out_size;

  dim3 blk(256);
  const int MR = Bc * Nc;  // 4096 rows

  // 0. detect input dtype.
  detect_kernel<<<dim3(1), dim3(64), 0, stream>>>(d_in[0], flag);

  ConvJobs jobs;
  for (int i = 0; i < 18; ++i) { jobs.j[i].src = d_in[i]; jobs.j[i].dst = cin[i]; jobs.j[i].n = in_sizes[i]; }
  jobs.j[0].n = 0;   // x       -> ln_kernel reads d_in[0] raw (residual)
  jobs.j[1].n = 0;   // memory  -> prep split reads d_in[1]
  jobs.j[2].n = 0;   // W_qvk   -> prep wsplit reads d_in[2]
  jobs.j[4].n = 0;   // W_kv
  jobs.j[6].n = 0;   // W_q
  jobs.j[8].n = 0;   // W_ff1
  jobs.j[10].n = 0;  // W_ff2

  const float *b_qvk = cin[3], *b_kv = cin[5], *b_q = cin[7],
              *b_ff1 = cin[9], *b_ff2 = cin[11],
              *ln1_g = cin[12], *ln1_b = cin[13], *ln2_g = cin[14], *ln2_b = cin[15],
              *ln3_g = cin[16], *ln3_b = cin[17];

  WJobs wj;
  wj.j[0] = WJob{d_in[2],  B2_qvk, DIMc, 3 * DIMc, 24, 0};    // 24x8  = 192
  wj.j[1] = WJob{d_in[4],  B2_kv,  DIMc, 2 * DIMc, 16, 192};  // 16x8  = 128
  wj.j[2] = WJob{d_in[6],  B2_q,   DIMc, DIMc,      8, 320};  // 8x8   = 64
  wj.j[3] = WJob{d_in[8],  B2_ff1, DIMc, FFc,      32, 384};  // 32x8  = 256
  wj.j[4] = WJob{d_in[10], B2_ff2, FFc,  DIMc,      8, 640};  // 8x32  = 256 -> 896

  // 0b. ONE fused prep launch: weight splits + activation splits + small ingest
  //     + zero(colsum..ctx2). 896 + 1024 + 36 + 65 = 2021 blocks.
  prep_kernel<<<dim3(2021), blk, 0, stream>>>(
      wj, jobs, d_in[0], d_in[1], A2slotA, A2slotC, colsum, flag);

  // 1. qvk = x @ W_qvk + b  (BN=128; A raw -> exact when bf16: 1 product)
  gemm_mfma<128, 128, 1, 0, false, false, true><<<dim3(12, 32), blk, 0, stream>>>(
      A2slotA, B2_qvk, b_qvk, nullptr, qvk, nullptr, 3 * DIMc, DIMc, flag);
  // 2. causal linear self-attention
  causalA<<<dim3(NCc, Bc * Hc), blk, 0, stream>>>(qvk, chunkKV, chunkKs);
  causalB<<<dim3(16, 17), blk, 0, stream>>>(chunkKV, chunkKs);
  causalC<<<dim3(NCc, Bc * Hc), blk, 0, stream>>>(qvk, chunkKV, chunkKs, attn_o);
  // 3. LN1(attn + x[raw]) -> out1 fp32 + split into slotB (q2 GEMM A)
  ln_kernel<true, true, false, true><<<dim3(MR), blk, 0, stream>>>(
      attn_o, d_in[0], ln1_g, ln1_b, out1, A2slotB, flag);
  // 4. kv = memory @ W_kv + b (BN=128); q2 split-K=2 (attn2 consumes partials)
  gemm_mfma<128, 128, 1, 0, false, false, true><<<dim3(8, 32), blk, 0, stream>>>(
      A2slotC, B2_kv, b_kv, nullptr, kvbuf, nullptr, 2 * DIMc, DIMc, flag);
  gemm_mfma<128, 64, 2, 2, false, false, false><<<dim3(8, 32, 2), blk, 0, stream>>>(
      A2slotB, B2_q, nullptr, nullptr, partials, nullptr, DIMc, DIMc, flag);
  // 5. cross linear attention (ctx transposed; colsum/ctx2 pre-zeroed by prep)
  ctx_kernel<<<dim3(Mc / 64, Bc * Hc), blk, 0, stream>>>(kvbuf, colsum, ctx2);
  attn2_kernel<<<dim3(Nc / 64, Bc * Hc), blk, 0, stream>>>(
      partials, b_q, ctx2, colsum, attn2_o);
  // 6. LN2(attn2 + out1) in-place -> ybuf fp32 + split into slotA (ff1 A)
  ln_kernel<true, false, false, true><<<dim3(MR), blk, 0, stream>>>(
      attn2_o, out1, ln2_g, ln2_b, ybuf, A2slotA, flag);
  // 7. FF: ff1 (BN=128) writes [hi|lo] split; ff2 (BN=128, split-K=4) -> partials
  gemm_mfma<128, 128, 1, 1, true, false, false><<<dim3(16, 32), blk, 0, stream>>>(
      A2slotA, B2_ff1, b_ff1, nullptr, nullptr, O2ff, FFc, DIMc, flag);
  gemm_mfma<128, 128, 4, 2, false, false, false><<<dim3(4, 32, 4), blk, 0, stream>>>(
      O2ff, B2_ff2, nullptr, nullptr, partials, nullptr, DIMc, FFc, flag);
  // 8. LN3(sum partials + bias + ybuf) -> d_out (bf16 or fp32 per flag)
  ln3_fused<<<dim3(MR), blk, 0, stream>>>(
      partials, b_ff2, ybuf, ln3_g, ln3_b, d_out, flag);
}

// Round 15
// 324.562 us; speedup vs baseline: 1.0370x; 1.0370x over previous
//
#include <hip/hip_runtime.h>
#include <hip/hip_bf16.h>

#define DEV __device__ __forceinline__

constexpr int Bc = 2, Nc = 2048, Mc = 2048, DIMc = 512, Hc = 8, FFc = 2048, Ec = 64;
constexpr int CT = 64;            // causal chunk length (tokens)
constexpr int NCc = Nc / CT;      // 32 chunks per sequence
constexpr float LN_EPS = 1e-5f, ATTN_EPS = 1e-6f;

typedef __bf16 bfrag8 __attribute__((ext_vector_type(8)));
typedef float ffrag4 __attribute__((ext_vector_type(4)));
typedef unsigned short u16;

// ---------------- helpers ----------------
DEV u16 f2bf(float v) {
  __hip_bfloat16 h = __float2bfloat16(v);   // RTN-even
  return __builtin_bit_cast(unsigned short, h);
}
DEV float bf2f(u16 u) { return __uint_as_float(((unsigned)u) << 16); }

DEV void gload16(const void* g, void* l) {
  __builtin_amdgcn_global_load_lds(
      (const __attribute__((address_space(1))) void*)g,
      (__attribute__((address_space(3))) void*)l, 16, 0, 0);
}

// XOR swizzle for [64][64] u16 LDS tiles (row stride 128B) — causalC/attn2.
DEV int SW(int r, int c) { return r * 64 + (c ^ ((r & 7) << 3)); }

// GEMM-tile swizzle: [rows][32] u16 (64B rows). 16B-chunk index XORed with
// (row>>1)&3. Zero bank conflicts (verified round 8).
DEV int SWK(int r, int c) { return r * 32 + ((c ^ ((r >> 1) & 3)) << 3); }

// ---------------- dtype detection ----------------
__global__ __launch_bounds__(64) void detect_kernel(const void* x, int* flag) {
  const unsigned short* u = (const unsigned short*)x;
  int tid = threadIdx.x;
  int bad = 0;
#pragma unroll
  for (int i = 0; i < 8; ++i) {
    float v = __uint_as_float(((unsigned)u[tid * 8 + i]) << 16);
    if (!(fabsf(v) <= 1e4f)) bad = 1;   // catches NaN, Inf, garbage
  }
  unsigned long long m = __ballot(bad);
  if (tid == 0) *flag = (m == 0ull) ? 1 : 0;  // 1 = inputs are bf16
}

// ---------------- job structs ----------------
struct ConvJob { const void* src; float* dst; int n; };
struct ConvJobs { ConvJob j[18]; };
struct WJob { const void* src; u16* dst; int K; int N; int tx; int base; };
struct WJobs { WJob j[5]; };

// ---------------- FUSED prep: one launch does all preprocessing -------------------
// Block ranges: [0,896) weight transpose+split; [896,1920) activation splits
// (x -> outA, memory -> outC); [1920,1956) small-array fp32 ingest;
// [1956,2021) zero colsum+ctx2 (replaces hipMemsetAsync).
__global__ __launch_bounds__(256) void prep_kernel(WJobs wjobs, ConvJobs cjobs,
    const void* __restrict__ xin, const void* __restrict__ memin,
    u16* __restrict__ outA, u16* __restrict__ outC,
    float* __restrict__ zbase, const int* __restrict__ flag)
{
  const int bf = *flag;
  const int blk = blockIdx.x;
  const int tid = threadIdx.x;
  __shared__ float T[64][65];

  if (blk < 896) {
    int ji = 0;
#pragma unroll
    for (int t = 1; t < 5; ++t) if (blk >= wjobs.j[t].base) ji = t;
    WJob jb = wjobs.j[ji];
    int tti = blk - jb.base;
    int bx = tti % jb.tx, by = tti / jb.tx;
    const int K = jb.K, N = jb.N;
    const void* W = jb.src;
    u16* B2t = jb.dst;
    int n0 = bx * 64, k0 = by * 64;
#pragma unroll
    for (int j = 0; j < 16; ++j) {
      int idx = tid + 256 * j;
      int kl = idx >> 6, nl = idx & 63;
      size_t gi = (size_t)(k0 + kl) * N + n0 + nl;
      T[kl][nl] = bf ? bf2f(((const u16*)W)[gi]) : ((const float*)W)[gi];
    }
    __syncthreads();
#pragma unroll
    for (int j = 0; j < 16; ++j) {
      int idx = tid + 256 * j;
      int nl = idx >> 6, kl = idx & 63;
      float v = T[kl][nl];
      u16 hi = f2bf(v);
      u16 lo = f2bf(v - bf2f(hi));
      size_t rb = (size_t)(n0 + nl) * 2 * K + k0 + kl;
      B2t[rb]     = hi;
      B2t[rb + K] = lo;
    }
  } else if (blk < 1920) {
    int sub = blk - 896;
    int which = sub >> 9;           // 0: x, 1: memory
    int bx = sub & 511;
    const void* in = which ? memin : xin;
    u16* out = which ? outC : outA;
    const int K = DIMc;
    const int total = Bc * Nc * DIMc;
    int n8 = total >> 3;
    int stride = 512 * 256;
    for (int ii = bx * 256 + tid; ii < n8; ii += stride) {
      int i = ii * 8;
      float v[8];
      if (bf) {
        uint4 a = ((const uint4*)in)[ii];
        unsigned w[4] = {a.x, a.y, a.z, a.w};
#pragma unroll
        for (int j = 0; j < 4; ++j) {
          v[2 * j]     = bf2f((u16)(w[j] & 0xffff));
          v[2 * j + 1] = bf2f((u16)(w[j] >> 16));
        }
      } else {
        float4 a = ((const float4*)in)[2 * ii];
        float4 b = ((const float4*)in)[2 * ii + 1];
        v[0] = a.x; v[1] = a.y; v[2] = a.z; v[3] = a.w;
        v[4] = b.x; v[5] = b.y; v[6] = b.z; v[7] = b.w;
      }
      unsigned hw[4], lw[4];
#pragma unroll
      for (int j = 0; j < 4; ++j) {
        u16 h0 = f2bf(v[2 * j]),     l0 = f2bf(v[2 * j]     - bf2f(f2bf(v[2 * j])));
        u16 h1 = f2bf(v[2 * j + 1]), l1 = f2bf(v[2 * j + 1] - bf2f(f2bf(v[2 * j + 1])));
        hw[j] = (unsigned)h0 | ((unsigned)h1 << 16);
        lw[j] = (unsigned)l0 | ((unsigned)l1 << 16);
      }
      int row = i >> 9, k = i & (K - 1);
      size_t rb = (size_t)row * 2 * K + k;
      *(uint4*)&out[rb]     = uint4{hw[0], hw[1], hw[2], hw[3]};
      *(uint4*)&out[rb + K] = uint4{lw[0], lw[1], lw[2], lw[3]};
    }
  } else if (blk < 1956) {
    int s = blk - 1920;
    ConvJob jb = cjobs.j[s >> 1];
    int bx = s & 1;
    int n8 = jb.n >> 3;
    int stride = 2 * 256;
    for (int i = bx * 256 + tid; i < n8; i += stride) {
      float o[8];
      if (bf) {
        uint4 a = ((const uint4*)jb.src)[i];
        unsigned w[4] = {a.x, a.y, a.z, a.w};
#pragma unroll
        for (int j = 0; j < 4; ++j) {
          o[2 * j]     = bf2f((u16)(w[j] & 0xffff));
          o[2 * j + 1] = bf2f((u16)(w[j] >> 16));
        }
      } else {
        float4 a = ((const float4*)jb.src)[2 * i];
        float4 b = ((const float4*)jb.src)[2 * i + 1];
        o[0] = a.x; o[1] = a.y; o[2] = a.z; o[3] = a.w;
        o[4] = b.x; o[5] = b.y; o[6] = b.z; o[7] = b.w;
      }
      float4* d = (float4*)jb.dst;
      d[2 * i]     = float4{o[0], o[1], o[2], o[3]};
      d[2 * i + 1] = float4{o[4], o[5], o[6], o[7]};
    }
  } else {
    int zi = (blk - 1956) * 256 + tid;
    ((float4*)zbase)[zi] = float4{0.f, 0.f, 0.f, 0.f};
  }
}

// ---------------- MFMA GEMM: C[M,N] = A2[M,2K] @ B2t[N,2K]^T ----------------
// COUNTED-VMCNT double-buffered pipeline (T4). BN=128 gives FM=FN=4.
// Product set wave-uniform: fp32 = 3 products; bf16 = Bl==0; bf16+A_EXACT = 1.
// SWK swizzle both sides (0 conflicts). Bijective XCD swizzle.
template<int BM, int BN, int SPLITK, int OUTMODE, bool RELU, bool ADD_RES, bool A_EXACT>
__global__ __launch_bounds__(256) void gemm_mfma(
    const u16* __restrict__ A2, const u16* __restrict__ B2t,
    const float* __restrict__ bias, const float* __restrict__ res,
    float* __restrict__ Cf, u16* __restrict__ C2,
    int N, int K, const int* __restrict__ flagp)
{
  constexpr int WM = BM / 2, WN = BN / 2, FM = WM / 16, FN = WN / 16;
  __shared__ u16 A0h[BM * 32], A0l[BM * 32], B0h[BN * 32], B0l[BN * 32];
  __shared__ u16 A1h[BM * 32], A1l[BM * 32], B1h[BN * 32], B1l[BN * 32];
  const int bf = *flagp;
  const bool useBl = (bf == 0);             // weights exact when bf16
  const bool useAl = (bf == 0) || !A_EXACT; // raw-input A exact when bf16
  const int tid = threadIdx.x;
  const int lane = tid & 63, wid = tid >> 6;
  const int wr = wid >> 1, wc = wid & 1;
  const int gx = gridDim.x, gy = gridDim.y;
  const int nwg = gx * gy * gridDim.z;
  const int flat = (blockIdx.z * gy + blockIdx.y) * gx + blockIdx.x;
  const int v = (flat & 7) * (nwg >> 3) + (flat >> 3);
  const int bx = v % gx;
  const int rest = v / gx;
  const int by = rest % gy;
  const int bz = rest / gy;
  const int row0 = by * BM, col0 = bx * BN;
  const int Mtot = gy * BM;
  const int sr = lane >> 2;
  const int skl = (((lane & 3) ^ ((sr >> 1) & 3)) << 3);   // inverse-swz source chunk
  const int ar = lane & 15, kc = lane >> 4;                // fragment coords
  const size_t strA = (size_t)2 * K;

  ffrag4 acc[FM][FN];
#pragma unroll
  for (int m = 0; m < FM; ++m)
#pragma unroll
    for (int n = 0; n < FN; ++n) acc[m][n] = ffrag4{0.f, 0.f, 0.f, 0.f};

  const int Kseg = K / SPLITK;
  const int kbeg = bz * Kseg;
  const int nt = Kseg / 32;   // even at every call site

#define FENCE_ asm volatile("" ::: "memory")
#define BAR_ do { FENCE_; __builtin_amdgcn_s_barrier(); FENCE_; } while (0)
#define WAITV__(n) asm volatile("s_waitcnt vmcnt(" #n ")" ::: "memory")
#define WAITV_(n) WAITV__(n)

#define STAGE_(UA, UB, AH, AL, BH, BL, KK) do {                                      \
    for (int r = wid; r < BM / 16; r += 4) {                                         \
      gload16(&A2[(size_t)(row0 + r * 16 + sr) * strA + (KK) + skl],     &AH[r * 16 * 32]); \
      if (UA)                                                                        \
        gload16(&A2[(size_t)(row0 + r * 16 + sr) * strA + K + (KK) + skl], &AL[r * 16 * 32]); \
    }                                                                                \
    for (int r = wid; r < BN / 16; r += 4) {                                         \
      gload16(&B2t[(size_t)(col0 + r * 16 + sr) * strA + (KK) + skl],     &BH[r * 16 * 32]); \
      if (UB)                                                                        \
        gload16(&B2t[(size_t)(col0 + r * 16 + sr) * strA + K + (KK) + skl], &BL[r * 16 * 32]); \
    } } while (0)

#define COMPUTE_(UA, UB, AH, AL, BH, BL) do {                                        \
    bfrag8 afh[FM], bwh[FN];                                                         \
    _Pragma("unroll")                                                                \
    for (int m = 0; m < FM; ++m)                                                     \
      afh[m] = *(const bfrag8*)&AH[SWK(wr * WM + m * 16 + ar, kc)];                  \
    _Pragma("unroll")                                                                \
    for (int n = 0; n < FN; ++n)                                                     \
      bwh[n] = *(const bfrag8*)&BH[SWK(wc * WN + n * 16 + ar, kc)];                  \
    _Pragma("unroll")                                                                \
    for (int m = 0; m < FM; ++m)                                                     \
      _Pragma("unroll")                                                              \
      for (int n = 0; n < FN; ++n)                                                   \
        acc[m][n] = __builtin_amdgcn_mfma_f32_16x16x32_bf16(afh[m], bwh[n], acc[m][n], 0, 0, 0); \
    if (UB) {                                                                        \
      bfrag8 bwl[FN];                                                                \
      _Pragma("unroll")                                                              \
      for (int n = 0; n < FN; ++n)                                                   \
        bwl[n] = *(const bfrag8*)&BL[SWK(wc * WN + n * 16 + ar, kc)];                \
      _Pragma("unroll")                                                              \
      for (int m = 0; m < FM; ++m)                                                   \
        _Pragma("unroll")                                                            \
        for (int n = 0; n < FN; ++n)                                                 \
          acc[m][n] = __builtin_amdgcn_mfma_f32_16x16x32_bf16(afh[m], bwl[n], acc[m][n], 0, 0, 0); \
    }                                                                                \
    if (UA) {                                                                        \
      bfrag8 afl[FM];                                                                \
      _Pragma("unroll")                                                              \
      for (int m = 0; m < FM; ++m)                                                   \
        afl[m] = *(const bfrag8*)&AL[SWK(wr * WM + m * 16 + ar, kc)];                \
      _Pragma("unroll")                                                              \
      for (int m = 0; m < FM; ++m)                                                   \
        _Pragma("unroll")                                                            \
        for (int n = 0; n < FN; ++n)                                                 \
          acc[m][n] = __builtin_amdgcn_mfma_f32_16x16x32_bf16(afl[m], bwh[n], acc[m][n], 0, 0, 0); \
    } } while (0)

#define KLOOP_(L, UA, UB) do {                                                       \
    STAGE_(UA, UB, A0h, A0l, B0h, B0l, kbeg);                                        \
    for (int t = 0; t < nt; t += 2) {                                                \
      STAGE_(UA, UB, A1h, A1l, B1h, B1l, kbeg + (t + 1) * 32);                       \
      WAITV_(L);                                                                     \
      BAR_;                                                                          \
      COMPUTE_(UA, UB, A0h, A0l, B0h, B0l);                                          \
      BAR_;                                                                          \
      if (t + 2 < nt) { STAGE_(UA, UB, A0h, A0l, B0h, B0l, kbeg + (t + 2) * 32); WAITV_(L); } \
      else            { WAITV_(0); }                                                 \
      BAR_;                                                                          \
      COMPUTE_(UA, UB, A1h, A1l, B1h, B1l);                                          \
      BAR_;                                                                          \
    } } while (0)

  if constexpr (BN == 128) {
    if (useAl && useBl)      KLOOP_(8, 1, 1);   // fp32: 3 products
    else if (useAl)          KLOOP_(6, 1, 0);   // bf16, A inexact: 2 products
    else                     KLOOP_(4, 0, 0);   // bf16, A exact: 1 product
  } else {
    if (useAl && useBl)      KLOOP_(6, 1, 1);
    else if (useAl)          KLOOP_(5, 1, 0);
    else                     KLOOP_(3, 0, 0);
  }

#undef KLOOP_
#undef COMPUTE_
#undef STAGE_
#undef WAITV_
#undef WAITV__
#undef BAR_
#undef FENCE_

#pragma unroll
  for (int m = 0; m < FM; ++m) {
    int rbase = row0 + wr * WM + m * 16 + (lane >> 4) * 4;
#pragma unroll
    for (int n = 0; n < FN; ++n) {
      int col = col0 + wc * WN + n * 16 + ar;
#pragma unroll
      for (int u = 0; u < 4; ++u) {
        int row = rbase + u;
        float val = acc[m][n][u];
        if constexpr (OUTMODE == 2) {
          Cf[((size_t)bz * Mtot + row) * N + col] = val;
        } else {
          val += bias[col];
          if (ADD_RES) val += res[(size_t)row * N + col];
          if (RELU) val = fmaxf(val, 0.f);
          if constexpr (OUTMODE == 0) {
            Cf[(size_t)row * N + col] = val;
          } else {
            u16 hi = f2bf(val);
            u16 lo = f2bf(val - bf2f(hi));
            size_t rb = (size_t)row * 2 * N;
            C2[rb + col]     = hi;
            C2[rb + N + col] = lo;
          }
        }
      }
    }
  }
}

// ---------------- layernorm over last dim (512), optional residual ----------------
template<bool HAS_RES, bool RAW_RES, bool FINAL, bool OUTSPLIT>
__global__ __launch_bounds__(256) void ln_kernel(
    const float* __restrict__ in, const void* __restrict__ res,
    const float* __restrict__ g, const float* __restrict__ b,
    void* __restrict__ out, u16* __restrict__ out2, const int* __restrict__ flag)
{
  int row = blockIdx.x, tid = threadIdx.x;
  size_t base = (size_t)row * DIMc;
  float x0 = in[base + tid], x1 = in[base + tid + 256];
  if (HAS_RES) {
    if (RAW_RES) {
      if (*flag) {
        x0 += bf2f(((const u16*)res)[base + tid]);
        x1 += bf2f(((const u16*)res)[base + tid + 256]);
      } else {
        x0 += ((const float*)res)[base + tid];
        x1 += ((const float*)res)[base + tid + 256];
      }
    } else {
      x0 += ((const float*)res)[base + tid];
      x1 += ((const float*)res)[base + tid + 256];
    }
  }
  float s1 = x0 + x1, s2 = x0 * x0 + x1 * x1;
#pragma unroll
  for (int off = 1; off < 64; off <<= 1) { s1 += __shfl_xor(s1, off); s2 += __shfl_xor(s2, off); }
  __shared__ float p1[4], p2[4], stat[2];
  if ((tid & 63) == 0) { p1[tid >> 6] = s1; p2[tid >> 6] = s2; }
  __syncthreads();
  if (tid == 0) {
    float t1 = p1[0] + p1[1] + p1[2] + p1[3];
    float t2 = p2[0] + p2[1] + p2[2] + p2[3];
    float mu = t1 / DIMc;
    float var = t2 / DIMc - mu * mu;
    stat[0] = mu; stat[1] = rsqrtf(var + LN_EPS);
  }
  __syncthreads();
  float mu = stat[0], rv = stat[1];
  float y0 = (x0 - mu) * rv * g[tid] + b[tid];
  float y1 = (x1 - mu) * rv * g[tid + 256] + b[tid + 256];
  if (FINAL) {
    if (*flag) {
      __hip_bfloat16* o = (__hip_bfloat16*)out;
      o[base + tid] = __float2bfloat16(y0);
      o[base + tid + 256] = __float2bfloat16(y1);
    } else {
      float* o = (float*)out;
      o[base + tid] = y0;
      o[base + tid + 256] = y1;
    }
  } else {
    float* o = (float*)out;
    o[base + tid] = y0;
    o[base + tid + 256] = y1;
  }
  if (OUTSPLIT) {
    size_t rb = (size_t)row * 1024;
    u16 h0 = f2bf(y0);
    out2[rb + tid] = h0;
    out2[rb + 512 + tid] = f2bf(y0 - bf2f(h0));
    u16 h1 = f2bf(y1);
    out2[rb + tid + 256] = h1;
    out2[rb + 512 + tid + 256] = f2bf(y1 - bf2f(h1));
  }
}

// ---------------- fused split-K reduce (P=4) + bias + residual + LN3 -> d_out ------
__global__ __launch_bounds__(256) void ln3_fused(const float* __restrict__ part,
    const float* __restrict__ bias, const float* __restrict__ res,
    const float* __restrict__ g, const float* __restrict__ b,
    void* __restrict__ out, const int* __restrict__ flag)
{
  int row = blockIdx.x, tid = threadIdx.x;
  size_t base = (size_t)row * DIMc;
  float x0 = bias[tid] + res[base + tid];
  float x1 = bias[tid + 256] + res[base + tid + 256];
#pragma unroll
  for (int p = 0; p < 4; ++p) {
    x0 += part[(size_t)p * 2097152 + base + tid];
    x1 += part[(size_t)p * 2097152 + base + tid + 256];
  }
  float s1 = x0 + x1, s2 = x0 * x0 + x1 * x1;
#pragma unroll
  for (int off = 1; off < 64; off <<= 1) { s1 += __shfl_xor(s1, off); s2 += __shfl_xor(s2, off); }
  __shared__ float p1[4], p2[4], stat[2];
  if ((tid & 63) == 0) { p1[tid >> 6] = s1; p2[tid >> 6] = s2; }
  __syncthreads();
  if (tid == 0) {
    float t1 = p1[0] + p1[1] + p1[2] + p1[3];
    float t2 = p2[0] + p2[1] + p2[2] + p2[3];
    float mu = t1 / DIMc;
    float var = t2 / DIMc - mu * mu;
    stat[0] = mu; stat[1] = rsqrtf(var + LN_EPS);
  }
  __syncthreads();
  float mu = stat[0], rv = stat[1];
  float y0 = (x0 - mu) * rv * g[tid] + b[tid];
  float y1 = (x1 - mu) * rv * g[tid + 256] + b[tid + 256];
  if (*flag) {
    __hip_bfloat16* o = (__hip_bfloat16*)out;
    o[base + tid] = __float2bfloat16(y0);
    o[base + tid + 256] = __float2bfloat16(y1);
  } else {
    float* o = (float*)out;
    o[base + tid] = y0;
    o[base + tid + 256] = y1;
  }
}

// ---------------- causal linear attention, pass A: per-chunk KV sums ----------------
// Writes chunkKV TRANSPOSED: chunkKVT[e][d] = sum_t ks[t][d]*vs[t][e]
__global__ __launch_bounds__(256) void causalA(const float* __restrict__ qvk,
    float* __restrict__ chunkKVT, float* __restrict__ chunkKs)
{
  int c = blockIdx.x, bh = blockIdx.y;
  int b = bh >> 3, h = bh & 7;
  __shared__ float ks[CT][Ec];
  __shared__ float vs[CT][Ec];
  int tid = threadIdx.x;
#pragma unroll
  for (int j = 0; j < 16; ++j) {
    int i = tid + 256 * j;
    int t = i >> 6, d = i & 63;
    size_t rowbase = ((size_t)b * Nc + c * CT + t) * (3 * DIMc);
    ks[t][d] = __expf(qvk[rowbase + 2 * DIMc + h * Ec + d]);
    vs[t][d] = qvk[rowbase + DIMc + h * Ec + d];
  }
  __syncthreads();
  int e = tid & 63, d0 = tid >> 6;
  float acc[16] = {};
  for (int t = 0; t < CT; ++t) {
    float ve = vs[t][e];
#pragma unroll
    for (int j = 0; j < 16; ++j) acc[j] += ks[t][d0 + 4 * j] * ve;
  }
  size_t obase = ((size_t)bh * NCc + c) * (Ec * Ec);
#pragma unroll
  for (int j = 0; j < 16; ++j) chunkKVT[obase + (size_t)e * Ec + (d0 + 4 * j)] = acc[j];
  if (tid < Ec) {
    float s = 0;
    for (int t = 0; t < CT; ++t) s += ks[t][tid];
    chunkKs[((size_t)bh * NCc + c) * Ec + tid] = s;
  }
}

// ---------------- pass B: exclusive prefix over chunks (parallelized) ----------------
__global__ __launch_bounds__(256) void causalB(float* __restrict__ chunkKV,
                                               float* __restrict__ chunkKs)
{
  int bh = blockIdx.x, grp = blockIdx.y, tid = threadIdx.x;
  if (grp < 16) {
    int idx = grp * 256 + tid;
    float run = 0;
    size_t base = (size_t)bh * NCc * Ec * Ec + idx;
#pragma unroll
    for (int c = 0; c < NCc; ++c) {
      float t = chunkKV[base + (size_t)c * Ec * Ec];
      chunkKV[base + (size_t)c * Ec * Ec] = run;
      run += t;
    }
  } else if (tid < Ec) {
    float run = 0;
    size_t base = (size_t)bh * NCc * Ec + tid;
#pragma unroll
    for (int c = 0; c < NCc; ++c) {
      float t = chunkKs[base + (size_t)c * Ec];
      chunkKs[base + (size_t)c * Ec] = run;
      run += t;
    }
  }
}

// ---------------- pass C: per-token outputs via MFMA ----------------
__global__ __launch_bounds__(256) void causalC(const float* __restrict__ qvk,
    const float* __restrict__ chunkKVT, const float* __restrict__ chunkKs,
    float* __restrict__ attn_out)
{
  int c = blockIdx.x, bh = blockIdx.y;
  int b = bh >> 3, h = bh & 7;
  __shared__ u16 qsh[64 * 64], qsl[64 * 64];   // A: qs[t][d]
  __shared__ u16 ksPh[64 * 64], ksPl[64 * 64]; // B: ks[tau][d]  ->  A: Pm[t][tau]
  __shared__ u16 STh[64 * 64], STl[64 * 64];   // B: S^T[e][d]
  __shared__ u16 VTh[64 * 72], VTl[64 * 72];   // B: V^T[e][tau], pad 72
  __shared__ float kpre[Ec], r0[CT], dinv[CT];
  int tid = threadIdx.x;
  int lane = tid & 63, w = tid >> 6;
  const int ar = lane & 15, kb = (lane >> 4) * 8;
  size_t kvb = (size_t)bh * NCc + c;

  if (tid < Ec) kpre[tid] = chunkKs[kvb * Ec + tid] + ATTN_EPS;

  float qreg[16];
#pragma unroll
  for (int j = 0; j < 16; ++j) {
    int t = w * 16 + j, d = lane;
    size_t rowbase = ((size_t)b * Nc + c * CT + t) * (3 * DIMc);
    qreg[j] = qvk[rowbase + h * Ec + d];
    float kv = __expf(qvk[rowbase + 2 * DIMc + h * Ec + d]);
    u16 hi = f2bf(kv);
    ksPh[SW(t, d)] = hi; ksPl[SW(t, d)] = f2bf(kv - bf2f(hi));
    float vv = qvk[rowbase + DIMc + h * Ec + d];
    hi = f2bf(vv);
    VTh[d * 72 + t] = hi; VTl[d * 72 + t] = f2bf(vv - bf2f(hi));
    float sv = chunkKVT[kvb * (Ec * Ec) + (size_t)t * Ec + d];  // row e=t of S^T
    hi = f2bf(sv);
    STh[SW(t, d)] = hi; STl[SW(t, d)] = f2bf(sv - bf2f(hi));
  }
  __syncthreads();

  for (int ti = 0; ti < 16; ++ti) {
    int t = w * 16 + ti;
    float qv = qreg[ti];
    float mx = qv;
#pragma unroll
    for (int off = 1; off < 64; off <<= 1) mx = fmaxf(mx, __shfl_xor(mx, off));
    float ex = __expf(qv - mx);
    float ssum = ex;
#pragma unroll
    for (int off = 1; off < 64; off <<= 1) ssum += __shfl_xor(ssum, off);
    float qs = ex / ssum * 0.125f;
    float qk = qs * kpre[lane];
#pragma unroll
    for (int off = 1; off < 64; off <<= 1) qk += __shfl_xor(qk, off);
    if (lane == 0) r0[t] = qk;
    u16 hi = f2bf(qs);
    qsh[SW(t, lane)] = hi; qsl[SW(t, lane)] = f2bf(qs - bf2f(hi));
  }
  __syncthreads();

  ffrag4 pacc[4];
#pragma unroll
  for (int ct = 0; ct < 4; ++ct) pacc[ct] = ffrag4{0.f, 0.f, 0.f, 0.f};
#pragma unroll
  for (int ct = 0; ct < 4; ++ct)
#pragma unroll
    for (int k2 = 0; k2 < 64; k2 += 32) {
      bfrag8 ah = *(const bfrag8*)&qsh[SW(w * 16 + ar, k2 + kb)];
      bfrag8 al = *(const bfrag8*)&qsl[SW(w * 16 + ar, k2 + kb)];
      bfrag8 bh_ = *(const bfrag8*)&ksPh[SW(ct * 16 + ar, k2 + kb)];
      bfrag8 bl_ = *(const bfrag8*)&ksPl[SW(ct * 16 + ar, k2 + kb)];
      pacc[ct] = __builtin_amdgcn_mfma_f32_16x16x32_bf16(ah, bh_, pacc[ct], 0, 0, 0);
      pacc[ct] = __builtin_amdgcn_mfma_f32_16x16x32_bf16(ah, bl_, pacc[ct], 0, 0, 0);
      pacc[ct] = __builtin_amdgcn_mfma_f32_16x16x32_bf16(al, bh_, pacc[ct], 0, 0, 0);
    }
  __syncthreads();

  float rs[4] = {0.f, 0.f, 0.f, 0.f};
#pragma unroll
  for (int ct = 0; ct < 4; ++ct) {
    int tau = ct * 16 + ar;
#pragma unroll
    for (int u = 0; u < 4; ++u) {
      int t = w * 16 + (lane >> 4) * 4 + u;
      float pv = (tau <= t) ? pacc[ct][u] : 0.f;
      rs[u] += pv;
      u16 hi = f2bf(pv);
      ksPh[SW(t, tau)] = hi; ksPl[SW(t, tau)] = f2bf(pv - bf2f(hi));
    }
  }
#pragma unroll
  for (int u = 0; u < 4; ++u) {
    float vv = rs[u];
    vv += __shfl_xor(vv, 1); vv += __shfl_xor(vv, 2);
    vv += __shfl_xor(vv, 4); vv += __shfl_xor(vv, 8);
    if (ar == 0) {
      int t = w * 16 + (lane >> 4) * 4 + u;
      dinv[t] = 1.f / (r0[t] + vv);
    }
  }
  __syncthreads();

#pragma unroll
  for (int et = 0; et < 4; ++et) {
    ffrag4 oacc = ffrag4{0.f, 0.f, 0.f, 0.f};
#pragma unroll
    for (int k2 = 0; k2 < 64; k2 += 32) {
      bfrag8 ah = *(const bfrag8*)&qsh[SW(w * 16 + ar, k2 + kb)];
      bfrag8 al = *(const bfrag8*)&qsl[SW(w * 16 + ar, k2 + kb)];
      bfrag8 bh_ = *(const bfrag8*)&STh[SW(et * 16 + ar, k2 + kb)];
      bfrag8 bl_ = *(const bfrag8*)&STl[SW(et * 16 + ar, k2 + kb)];
      oacc = __builtin_amdgcn_mfma_f32_16x16x32_bf16(ah, bh_, oacc, 0, 0, 0);
      oacc = __builtin_amdgcn_mfma_f32_16x16x32_bf16(ah, bl_, oacc, 0, 0, 0);
      oacc = __builtin_amdgcn_mfma_f32_16x16x32_bf16(al, bh_, oacc, 0, 0, 0);
      bfrag8 ph = *(const bfrag8*)&ksPh[SW(w * 16 + ar, k2 + kb)];
      bfrag8 pl = *(const bfrag8*)&ksPl[SW(w * 16 + ar, k2 + kb)];
      bfrag8 vh = *(const bfrag8*)&VTh[(et * 16 + ar) * 72 + k2 + kb];
      bfrag8 vl = *(const bfrag8*)&VTl[(et * 16 + ar) * 72 + k2 + kb];
      oacc = __builtin_amdgcn_mfma_f32_16x16x32_bf16(ph, vh, oacc, 0, 0, 0);
      oacc = __builtin_amdgcn_mfma_f32_16x16x32_bf16(ph, vl, oacc, 0, 0, 0);
      oacc = __builtin_amdgcn_mfma_f32_16x16x32_bf16(pl, vh, oacc, 0, 0, 0);
    }
    int e = et * 16 + ar;
#pragma unroll
    for (int u = 0; u < 4; ++u) {
      int t = w * 16 + (lane >> 4) * 4 + u;
      attn_out[((size_t)b * Nc + c * CT + t) * DIMc + h * Ec + e] = oacc[u] * dinv[t];
    }
  }
}

// ---------------- cross-attn ctx via MFMA: ctxT[e][d] += Vs^T @ Ks  (+colsum) -------
// Per (slab,bh): C[64e x 64d] = sum_m Vs[m][e]*Ks[m][d], a 64x64x64 matmul.
// Operands staged TRANSPOSED hi/lo (pad-72 rows, 16B-aligned — causalC's VT layout);
// 3-product split accumulation (both operands inexact). Replaces the 1024-FMA
// serial VALU loop per thread with 24 MFMAs per wave.
__global__ __launch_bounds__(256) void ctx_kernel(const float* __restrict__ kvbuf,
    float* __restrict__ colsum, float* __restrict__ ctxT)
{
  int slab = blockIdx.x, bh = blockIdx.y;
  int b = bh >> 3, h = bh & 7;
  __shared__ u16 vth[64 * 72], vtl[64 * 72];   // A: Vs^T[e][m]
  __shared__ u16 kth[64 * 72], ktl[64 * 72];   // B: Ks^T[d][m]
  __shared__ float csum[4][Ec];
  int tid = threadIdx.x;
  int lane = tid & 63, w = tid >> 6;
  const int ar = lane & 15, kb = (lane >> 4) * 8;

  // stage: thread (w,lane) covers col=lane, rows m = w + 4j  (coalesced over lane)
  float psum = 0.f;
#pragma unroll
  for (int j = 0; j < 16; ++j) {
    int i = tid + 256 * j;
    int m = i >> 6, d = i & 63;   // d == lane, m == w + 4j
    size_t rowbase = ((size_t)b * Mc + slab * 64 + m) * (2 * DIMc);
    float kv = __expf(kvbuf[rowbase + h * Ec + d]);
    psum += kv;
    u16 hi = f2bf(kv);
    kth[d * 72 + m] = hi; ktl[d * 72 + m] = f2bf(kv - bf2f(hi));
    float vv = kvbuf[rowbase + DIMc + h * Ec + d];
    hi = f2bf(vv);
    vth[d * 72 + m] = hi; vtl[d * 72 + m] = f2bf(vv - bf2f(hi));
  }
  csum[w][lane] = psum;
  __syncthreads();
  if (tid < Ec)
    atomicAdd(&colsum[(size_t)bh * Ec + tid],
              csum[0][tid] + csum[1][tid] + csum[2][tid] + csum[3][tid]);

  // wave w owns e-rows [w*16, w*16+16); n-tile covers d-rows [n*16, n*16+16)
  size_t obase = (size_t)bh * Ec * Ec;
#pragma unroll
  for (int n = 0; n < 4; ++n) {
    ffrag4 acc = ffrag4{0.f, 0.f, 0.f, 0.f};
#pragma unroll
    for (int k2 = 0; k2 < 64; k2 += 32) {
      bfrag8 ah = *(const bfrag8*)&vth[(w * 16 + ar) * 72 + k2 + kb];
      bfrag8 al = *(const bfrag8*)&vtl[(w * 16 + ar) * 72 + k2 + kb];
      bfrag8 bh_ = *(const bfrag8*)&kth[(n * 16 + ar) * 72 + k2 + kb];
      bfrag8 bl_ = *(const bfrag8*)&ktl[(n * 16 + ar) * 72 + k2 + kb];
      acc = __builtin_amdgcn_mfma_f32_16x16x32_bf16(ah, bh_, acc, 0, 0, 0);
      acc = __builtin_amdgcn_mfma_f32_16x16x32_bf16(ah, bl_, acc, 0, 0, 0);
      acc = __builtin_amdgcn_mfma_f32_16x16x32_bf16(al, bh_, acc, 0, 0, 0);
    }
    int d = n * 16 + ar;
#pragma unroll
    for (int u = 0; u < 4; ++u) {
      int e = w * 16 + (lane >> 4) * 4 + u;
      atomicAdd(&ctxT[obase + (size_t)e * Ec + d], acc[u]);
    }
  }
}

// ---------------- cross-attn via MFMA, fused split-K reduce of q2 ----------------
__global__ __launch_bounds__(256) void attn2_kernel(const float* __restrict__ q2part,
    const float* __restrict__ bq, const float* __restrict__ ctxT,
    const float* __restrict__ colsum, float* __restrict__ out)
{
  int tc = blockIdx.x, bh = blockIdx.y;
  int b = bh >> 3, h = bh & 7;
  __shared__ u16 qsh[64 * 64], qsl[64 * 64];   // A: qs[t][d]
  __shared__ u16 cth[64 * 64], ctl[64 * 64];   // B: ctxT[e][d] (normalized)
  int tid = threadIdx.x;
  int lane = tid & 63, w = tid >> 6;
  const int ar = lane & 15, kb = (lane >> 4) * 8;
  const float bqv = bq[h * Ec + lane];

  // stage normalized ctxT split into LDS
#pragma unroll
  for (int j = 0; j < 16; ++j) {
    int i = tid + 256 * j;
    int r = i >> 6, d = i & 63;
    float v = ctxT[(size_t)bh * Ec * Ec + i] / colsum[(size_t)bh * Ec + d];
    u16 hi = f2bf(v);
    cth[SW(r, d)] = hi; ctl[SW(r, d)] = f2bf(v - bf2f(hi));
  }
  // softmax for this wave's 16 tokens; write qs split
  for (int ti = 0; ti < 16; ++ti) {
    int t = tc * 64 + w * 16 + ti;
    size_t qi = ((size_t)b * Nc + t) * DIMc + h * Ec + lane;
    float qv = q2part[qi] + q2part[(size_t)2097152 + qi] + bqv;
    float mx = qv;
#pragma unroll
    for (int off = 1; off < 64; off <<= 1) mx = fmaxf(mx, __shfl_xor(mx, off));
    float ex = __expf(qv - mx);
    float ssum = ex;
#pragma unroll
    for (int off = 1; off < 64; off <<= 1) ssum += __shfl_xor(ssum, off);
    float qs = ex / ssum * 0.125f;
    u16 hi = f2bf(qs);
    qsh[SW(w * 16 + ti, lane)] = hi; qsl[SW(w * 16 + ti, lane)] = f2bf(qs - bf2f(hi));
  }
  __syncthreads();

#pragma unroll
  for (int et = 0; et < 4; ++et) {
    ffrag4 oacc = ffrag4{0.f, 0.f, 0.f, 0.f};
#pragma unroll
    for (int k2 = 0; k2 < 64; k2 += 32) {
      bfrag8 ah = *(const bfrag8*)&qsh[SW(w * 16 + ar, k2 + kb)];
      bfrag8 al = *(const bfrag8*)&qsl[SW(w * 16 + ar, k2 + kb)];
      bfrag8 bh_ = *(const bfrag8*)&cth[SW(et * 16 + ar, k2 + kb)];
      bfrag8 bl_ = *(const bfrag8*)&ctl[SW(et * 16 + ar, k2 + kb)];
      oacc = __builtin_amdgcn_mfma_f32_16x16x32_bf16(ah, bh_, oacc, 0, 0, 0);
      oacc = __builtin_amdgcn_mfma_f32_16x16x32_bf16(ah, bl_, oacc, 0, 0, 0);
      oacc = __builtin_amdgcn_mfma_f32_16x16x32_bf16(al, bh_, oacc, 0, 0, 0);
    }
    int e = et * 16 + ar;
#pragma unroll
    for (int u = 0; u < 4; ++u) {
      int t = tc * 64 + w * 16 + (lane >> 4) * 4 + u;
      out[((size_t)b * Nc + t) * DIMc + h * Ec + e] = oacc[u];
    }
  }
}

extern "C" void kernel_launch(void* const* d_in, const int* in_sizes, int n_in,
                              void* d_out, int out_size, void* d_ws, size_t ws_size,
                              hipStream_t stream)
{
  float* ws = (float*)d_ws;
  int* flag = (int*)ws;
  float* conv = ws + 64;

  float* cin[18];
  size_t off = 0;
  for (int i = 0; i < 18; ++i) { cin[i] = conv + off; off += (size_t)in_sizes[i]; }
  float* pipe = conv + off;

  const size_t SZ_ROW = (size_t)Bc * Nc * DIMc;            // 2,097,152
  const size_t SZ_KV  = (size_t)Bc * Mc * 2 * DIMc;        // 4,194,304
  const size_t SZ_R0  = 12582912;                          // region0 span (f-eq)

  float* region0 = pipe;
  float* qvk     = region0;                   // live: gemm1 .. causalC
  float* kvbuf   = region0;                   // live: kvGEMM .. ctx_kernel
  u16*   O2ff    = (u16*)region0;             // live: ff1 .. ff2 ([hi|lo], 8.39M f-eq)
  float* out1    = region0 + SZ_R0;           // live: LN1 .. LN2
  float* attn_o  = out1 + SZ_ROW;             // attn_o -> attn2_o -> ybuf
  float* r3      = attn_o + SZ_ROW;           // chunkKV
  float* chunkKV = r3;
  float* chunkKs = r3 + SZ_ROW;                                   // 32768
  float* colsum  = chunkKs + (size_t)Bc * Hc * NCc * Ec;          // 1024
  float* ctx2    = colsum + (size_t)Bc * Hc * Ec;                 // 65536 (transposed)
  float* ybuf    = attn_o;
  float* attn2_o = attn_o;

  u16* B2_qvk = (u16*)(ctx2 + (size_t)Bc * Hc * Ec * Ec);
  u16* B2_kv  = B2_qvk + (size_t)(3 * DIMc) * (2 * DIMc);   // 1536 x 1024
  u16* B2_q   = B2_kv  + (size_t)(2 * DIMc) * (2 * DIMc);   // 1024 x 1024
  u16* B2_ff1 = B2_q   + (size_t)DIMc * (2 * DIMc);         // 512 x 1024
  u16* B2_ff2 = B2_ff1 + (size_t)FFc  * (2 * DIMc);         // 2048 x 1024
  u16* A2slotA = B2_ff2 + (size_t)DIMc * (2 * FFc);         // 4096 x 1024 (x -> ybuf)
  u16* A2slotB = A2slotA + (size_t)4096 * 1024;             // 4096 x 1024 (out1)
  u16* A2slotC = A2slotB + (size_t)4096 * 1024;             // 4096 x 1024 (memory)
  float* partials = (float*)(A2slotC + (size_t)4096 * 1024);// 4 x 2,097,152 fp32
  (void)ws_size; (void)n_in; (void)out_size;

  dim3 blk(256);
  const int MR = Bc * Nc;  // 4096 rows

  // 0. detect input dtype.
  detect_kernel<<<dim3(1), dim3(64), 0, stream>>>(d_in[0], flag);

  ConvJobs jobs;
  for (int i = 0; i < 18; ++i) { jobs.j[i].src = d_in[i]; jobs.j[i].dst = cin[i]; jobs.j[i].n = in_sizes[i]; }
  jobs.j[0].n = 0;   // x       -> ln_kernel reads d_in[0] raw (residual)
  jobs.j[1].n = 0;   // memory  -> prep split reads d_in[1]
  jobs.j[2].n = 0;   // W_qvk   -> prep wsplit reads d_in[2]
  jobs.j[4].n = 0;   // W_kv
  jobs.j[6].n = 0;   // W_q
  jobs.j[8].n = 0;   // W_ff1
  jobs.j[10].n = 0;  // W_ff2

  const float *b_qvk = cin[3], *b_kv = cin[5], *b_q = cin[7],
              *b_ff1 = cin[9], *b_ff2 = cin[11],
              *ln1_g = cin[12], *ln1_b = cin[13], *ln2_g = cin[14], *ln2_b = cin[15],
              *ln3_g = cin[16], *ln3_b = cin[17];

  WJobs wj;
  wj.j[0] = WJob{d_in[2],  B2_qvk, DIMc, 3 * DIMc, 24, 0};    // 24x8  = 192
  wj.j[1] = WJob{d_in[4],  B2_kv,  DIMc, 2 * DIMc, 16, 192};  // 16x8  = 128
  wj.j[2] = WJob{d_in[6],  B2_q,   DIMc, DIMc,      8, 320};  // 8x8   = 64
  wj.j[3] = WJob{d_in[8],  B2_ff1, DIMc, FFc,      32, 384};  // 32x8  = 256
  wj.j[4] = WJob{d_in[10], B2_ff2, FFc,  DIMc,      8, 640};  // 8x32  = 256 -> 896

  // 0b. ONE fused prep launch: weight splits + activation splits + small ingest
  //     + zero(colsum..ctx2). 896 + 1024 + 36 + 65 = 2021 blocks.
  prep_kernel<<<dim3(2021), blk, 0, stream>>>(
      wj, jobs, d_in[0], d_in[1], A2slotA, A2slotC, colsum, flag);

  // 1. qvk = x @ W_qvk + b  (BN=128; A raw -> exact when bf16: 1 product)
  gemm_mfma<128, 128, 1, 0, false, false, true><<<dim3(12, 32), blk, 0, stream>>>(
      A2slotA, B2_qvk, b_qvk, nullptr, qvk, nullptr, 3 * DIMc, DIMc, flag);
  // 2. causal linear self-attention
  causalA<<<dim3(NCc, Bc * Hc), blk, 0, stream>>>(qvk, chunkKV, chunkKs);
  causalB<<<dim3(16, 17), blk, 0, stream>>>(chunkKV, chunkKs);
  causalC<<<dim3(NCc, Bc * Hc), blk, 0, stream>>>(qvk, chunkKV, chunkKs, attn_o);
  // 3. LN1(attn + x[raw]) -> out1 fp32 + split into slotB (q2 GEMM A)
  ln_kernel<true, true, false, true><<<dim3(MR), blk, 0, stream>>>(
      attn_o, d_in[0], ln1_g, ln1_b, out1, A2slotB, flag);
  // 4. kv = memory @ W_kv + b (BN=128); q2 split-K=2 (attn2 consumes partials)
  gemm_mfma<128, 128, 1, 0, false, false, true><<<dim3(8, 32), blk, 0, stream>>>(
      A2slotC, B2_kv, b_kv, nullptr, kvbuf, nullptr, 2 * DIMc, DIMc, flag);
  gemm_mfma<128, 64, 2, 2, false, false, false><<<dim3(8, 32, 2), blk, 0, stream>>>(
      A2slotB, B2_q, nullptr, nullptr, partials, nullptr, DIMc, DIMc, flag);
  // 5. cross linear attention (ctx MFMA-ized; colsum/ctx2 pre-zeroed by prep)
  ctx_kernel<<<dim3(Mc / 64, Bc * Hc), blk, 0, stream>>>(kvbuf, colsum, ctx2);
  attn2_kernel<<<dim3(Nc / 64, Bc * Hc), blk, 0, stream>>>(
      partials, b_q, ctx2, colsum, attn2_o);
  // 6. LN2(attn2 + out1) in-place -> ybuf fp32 + split into slotA (ff1 A)
  ln_kernel<true, false, false, true><<<dim3(MR), blk, 0, stream>>>(
      attn2_o, out1, ln2_g, ln2_b, ybuf, A2slotA, flag);
  // 7. FF: ff1 (BN=128) writes [hi|lo] split; ff2 (BN=128, split-K=4) -> partials
  gemm_mfma<128, 128, 1, 1, true, false, false><<<dim3(16, 32), blk, 0, stream>>>(
      A2slotA, B2_ff1, b_ff1, nullptr, nullptr, O2ff, FFc, DIMc, flag);
  gemm_mfma<128, 128, 4, 2, false, false, false><<<dim3(4, 32, 4), blk, 0, stream>>>(
      O2ff, B2_ff2, nullptr, nullptr, partials, nullptr, DIMc, FFc, flag);
  // 8. LN3(sum partials + bias + ybuf) -> d_out (bf16 or fp32 per flag)
  ln3_fused<<<dim3(MR), blk, 0, stream>>>(
      partials, b_ff2, ybuf, ln3_g, ln3_b, d_out, flag);
}